// Round 5
// baseline (1346.148 us; speedup 1.0000x reference)
//
#include <hip/hip_runtime.h>
#include <hip/hip_bf16.h>

// MoE FFN, top-1 switch routing. fp32 end-to-end (no fp32 MFMA on CDNA4).
// Sparse dispatch: each token only runs through its argmax expert (exact
// same math as the dense reference's gather of y[route_idx, arange(n)]).
//
// GEMM2 (N=1024) is split-K=4 to restore block-level parallelism:
// ~275 working blocks -> ~1100. Partial s=0 lands in d_out, s=1..3 in ws;
// a reduce kernel applies sum + bias + route_p.
//
// Workspace: 16K +16K +256B +128K + H 64MiB + partials 48MiB = ~112.2 MiB.

#define D_MODEL 1024
#define MLP_DIM 4096
#define N_EXPERTS 8
#define N_TOK 4096
#define KSPLIT 4

// ---------------- router: logits -> softmax max prob + argmax ----------------
__global__ __launch_bounds__(64) void router_kernel(
    const float* __restrict__ x, const float* __restrict__ w_gate,
    const float* __restrict__ b_gate, int* __restrict__ route_idx,
    float* __restrict__ route_p) {
  int t = blockIdx.x;
  int lane = threadIdx.x;
  const float* xr = x + (size_t)t * D_MODEL;
  float acc[N_EXPERTS];
#pragma unroll
  for (int e = 0; e < N_EXPERTS; ++e) acc[e] = 0.f;
#pragma unroll
  for (int i = 0; i < D_MODEL / 64; ++i) {
    int idx = i * 64 + lane;
    float xv = xr[idx];
    const float* wg = w_gate + (size_t)idx * N_EXPERTS;
#pragma unroll
    for (int e = 0; e < N_EXPERTS; ++e) acc[e] += xv * wg[e];
  }
#pragma unroll
  for (int off = 32; off >= 1; off >>= 1) {
#pragma unroll
    for (int e = 0; e < N_EXPERTS; ++e) acc[e] += __shfl_xor(acc[e], off, 64);
  }
  if (lane == 0) {
    float l[N_EXPERTS];
#pragma unroll
    for (int e = 0; e < N_EXPERTS; ++e) l[e] = acc[e] + b_gate[e];
    // strict > : first-max tiebreak, matches jnp.argmax (softmax is monotonic)
    float m = l[0];
    int bi = 0;
#pragma unroll
    for (int e = 1; e < N_EXPERTS; ++e) {
      if (l[e] > m) { m = l[e]; bi = e; }
    }
    float s = 0.f;
#pragma unroll
    for (int e = 0; e < N_EXPERTS; ++e) s += expf(l[e] - m);
    route_idx[t] = bi;
    route_p[t] = 1.0f / s;  // max softmax prob = exp(0)/sum
  }
}

// ---------------- bucketize tokens per expert ----------------
__global__ void bucket_kernel(const int* __restrict__ route_idx,
                              int* __restrict__ counts,
                              int* __restrict__ bucket) {
  int t = blockIdx.x * blockDim.x + threadIdx.x;
  if (t < N_TOK) {
    int e = route_idx[t];
    int pos = atomicAdd(&counts[e], 1);
    bucket[e * N_TOK + pos] = t;
  }
}

// ---------------- gathered expert GEMM ----------------
// 128x128 tile, BK=16, 256 threads, 8x8 micro-tile as 2x2 blocks of 4x4
// (rows/cols {q*4, q*4+64}): LDS reads are broadcast + <=2-way bank alias
// (free on CDNA4, m136). Register prefetch of the next k-tile issued before
// the FMA block hides global latency under 2048 VALU-cycles of compute.
// SPLIT=false (layer 1): C = relu(A@W1 + b1) -> H, grid.z = expert
// SPLIT=true  (layer 2): raw partial A@W2 k-slice, grid.z = expert*4 + s,
//                        s==0 -> d_out, s>0 -> partials[s-1]
template <bool SPLIT>
__global__ __launch_bounds__(256) void expert_gemm(
    const float* __restrict__ A, const float* __restrict__ B,
    const float* __restrict__ bias, float* __restrict__ C0,
    float* __restrict__ partials, const int* __restrict__ bucket,
    const int* __restrict__ counts, int Kstride, int Ncols) {
  constexpr int BM = 128, BN = 128, BK = 16;
  constexpr int LDA = BM + 4, LDB = BN + 4;  // break pow2 strides
  int e, kbeg, kend;
  float* Cp;
  if (SPLIT) {
    e = blockIdx.z >> 2;
    int s = blockIdx.z & 3;
    kbeg = s * (MLP_DIM / KSPLIT);
    kend = kbeg + (MLP_DIM / KSPLIT);
    Cp = (s == 0) ? C0 : partials + (size_t)(s - 1) * N_TOK * D_MODEL;
  } else {
    e = blockIdx.z;
    kbeg = 0;
    kend = Kstride;
    Cp = C0;
  }
  int cnt = counts[e];
  int row0 = blockIdx.y * BM;
  if (row0 >= cnt) return;
  int col0 = blockIdx.x * BN;

  __shared__ float As[BK][LDA];  // k-major (transposed store)
  __shared__ float Bs[BK][LDB];
  __shared__ int tokS[BM];

  int tid = threadIdx.x;
  if (tid < BM) {
    int r = row0 + tid;
    tokS[tid] = (r < cnt) ? bucket[e * N_TOK + r] : -1;
  }
  __syncthreads();

  // A-load map: rows {ar, ar+64}, k-chunk ak (4 floats)
  const int ar = tid >> 2;
  const int ak = (tid & 3) * 4;
  // B-load map: k-row bk, col-chunk bj (8 floats = 2 float4)
  const int bk = tid >> 4;
  const int bj = (tid & 15) * 8;

  const int tx = tid & 15;  // cols tx*4 and tx*4+64
  const int ty = tid >> 4;  // rows ty*4 and ty*4+64

  float acc[2][2][4][4];
#pragma unroll
  for (int hm = 0; hm < 2; ++hm)
#pragma unroll
    for (int hn = 0; hn < 2; ++hn)
#pragma unroll
      for (int i = 0; i < 4; ++i)
#pragma unroll
        for (int j = 0; j < 4; ++j) acc[hm][hn][i][j] = 0.f;

  const int tok0 = tokS[ar], tok1 = tokS[ar + 64];
  const float* __restrict__ Ap0 =
      (tok0 >= 0) ? A + (size_t)tok0 * Kstride + ak : nullptr;
  const float* __restrict__ Ap1 =
      (tok1 >= 0) ? A + (size_t)tok1 * Kstride + ak : nullptr;
  const float* __restrict__ Bp =
      B + (size_t)e * Kstride * Ncols + (size_t)bk * Ncols + col0 + bj;

  float4 a0, a1, b0, b1;
  a0 = make_float4(0.f, 0.f, 0.f, 0.f);
  a1 = a0;
  if (Ap0) a0 = *(const float4*)(Ap0 + kbeg);
  if (Ap1) a1 = *(const float4*)(Ap1 + kbeg);
  {
    const float* bp = Bp + (size_t)kbeg * Ncols;
    b0 = *(const float4*)bp;
    b1 = *(const float4*)(bp + 4);
  }

  for (int k0 = kbeg; k0 < kend; k0 += BK) {
    __syncthreads();  // previous compute done before overwrite
    As[ak + 0][ar] = a0.x; As[ak + 1][ar] = a0.y;
    As[ak + 2][ar] = a0.z; As[ak + 3][ar] = a0.w;
    As[ak + 0][ar + 64] = a1.x; As[ak + 1][ar + 64] = a1.y;
    As[ak + 2][ar + 64] = a1.z; As[ak + 3][ar + 64] = a1.w;
    *(float4*)&Bs[bk][bj] = b0;
    *(float4*)&Bs[bk][bj + 4] = b1;
    __syncthreads();

    if (k0 + BK < kend) {  // prefetch next tile into regs (overlaps compute)
      int kn = k0 + BK;
      a0 = make_float4(0.f, 0.f, 0.f, 0.f);
      a1 = a0;
      if (Ap0) a0 = *(const float4*)(Ap0 + kn);
      if (Ap1) a1 = *(const float4*)(Ap1 + kn);
      const float* bp = Bp + (size_t)kn * Ncols;
      b0 = *(const float4*)bp;
      b1 = *(const float4*)(bp + 4);
    }

#pragma unroll
    for (int kk = 0; kk < BK; ++kk) {
      float av[2][4], bv[2][4];
      *(float4*)&av[0][0] = *(const float4*)&As[kk][ty * 4];
      *(float4*)&av[1][0] = *(const float4*)&As[kk][ty * 4 + 64];
      *(float4*)&bv[0][0] = *(const float4*)&Bs[kk][tx * 4];
      *(float4*)&bv[1][0] = *(const float4*)&Bs[kk][tx * 4 + 64];
#pragma unroll
      for (int hm = 0; hm < 2; ++hm)
#pragma unroll
        for (int hn = 0; hn < 2; ++hn)
#pragma unroll
          for (int i = 0; i < 4; ++i)
#pragma unroll
            for (int j = 0; j < 4; ++j)
              acc[hm][hn][i][j] += av[hm][i] * bv[hn][j];
    }
  }

  if (SPLIT) {
    // raw k-slice partial, no bias/epilogue
#pragma unroll
    for (int hm = 0; hm < 2; ++hm) {
#pragma unroll
      for (int i = 0; i < 4; ++i) {
        int r = hm * 64 + ty * 4 + i;
        if (row0 + r < cnt) {
          int tok = tokS[r];
#pragma unroll
          for (int hn = 0; hn < 2; ++hn) {
            float4 o;
            o.x = acc[hm][hn][i][0]; o.y = acc[hm][hn][i][1];
            o.z = acc[hm][hn][i][2]; o.w = acc[hm][hn][i][3];
            *(float4*)(Cp + (size_t)tok * Ncols + col0 + hn * 64 + tx * 4) = o;
          }
        }
      }
    }
  } else {
    float4 bvv[2];
    bvv[0] = *(const float4*)(bias + (size_t)e * Ncols + col0 + tx * 4);
    bvv[1] = *(const float4*)(bias + (size_t)e * Ncols + col0 + tx * 4 + 64);
#pragma unroll
    for (int hm = 0; hm < 2; ++hm) {
#pragma unroll
      for (int i = 0; i < 4; ++i) {
        int r = hm * 64 + ty * 4 + i;
        if (row0 + r < cnt) {
          int tok = tokS[r];
#pragma unroll
          for (int hn = 0; hn < 2; ++hn) {
            const float* bb = (const float*)&bvv[hn];
            float4 o;
            o.x = fmaxf(acc[hm][hn][i][0] + bb[0], 0.f);
            o.y = fmaxf(acc[hm][hn][i][1] + bb[1], 0.f);
            o.z = fmaxf(acc[hm][hn][i][2] + bb[2], 0.f);
            o.w = fmaxf(acc[hm][hn][i][3] + bb[3], 0.f);
            *(float4*)(Cp + (size_t)tok * Ncols + col0 + hn * 64 + tx * 4) = o;
          }
        }
      }
    }
  }
}

// ---------------- split-K reduce + bias + route_p epilogue ----------------
// one block per token, 256 threads = 256 float4 covering D_MODEL=1024 cols.
__global__ __launch_bounds__(256) void moe_reduce_kernel(
    float* __restrict__ out, const float* __restrict__ partials,
    const float* __restrict__ b2, const int* __restrict__ route_idx,
    const float* __restrict__ route_p) {
  int tok = blockIdx.x;
  int c = threadIdx.x * 4;
  int e = route_idx[tok];
  float p = route_p[tok];
  size_t off = (size_t)tok * D_MODEL + c;
  float4 s = *(const float4*)(out + off);
  const size_t stride = (size_t)N_TOK * D_MODEL;
#pragma unroll
  for (int sp = 0; sp < KSPLIT - 1; ++sp) {
    float4 v = *(const float4*)(partials + sp * stride + off);
    s.x += v.x; s.y += v.y; s.z += v.z; s.w += v.w;
  }
  float4 bv = *(const float4*)(b2 + (size_t)e * D_MODEL + c);
  s.x = (s.x + bv.x) * p;
  s.y = (s.y + bv.y) * p;
  s.z = (s.z + bv.z) * p;
  s.w = (s.w + bv.w) * p;
  *(float4*)(out + off) = s;
}

extern "C" void kernel_launch(void* const* d_in, const int* in_sizes, int n_in,
                              void* d_out, int out_size, void* d_ws,
                              size_t ws_size, hipStream_t stream) {
  const float* x = (const float*)d_in[0];
  const float* w_gate = (const float*)d_in[1];
  const float* b_gate = (const float*)d_in[2];
  const float* W1 = (const float*)d_in[3];
  const float* b1 = (const float*)d_in[4];
  const float* W2 = (const float*)d_in[5];
  const float* b2 = (const float*)d_in[6];
  float* out = (float*)d_out;

  // workspace layout (~112.2 MiB)
  char* ws = (char*)d_ws;
  int* route_idx = (int*)ws;                        // 16 KiB
  float* route_p = (float*)(ws + 16384);            // 16 KiB
  int* counts = (int*)(ws + 32768);                 // 32 B (pad to 256)
  int* bucket = (int*)(ws + 33024);                 // 128 KiB
  float* H = (float*)(ws + 164096);                 // 64 MiB
  float* partials = (float*)(ws + 164096 + (size_t)67108864);  // 48 MiB (3 slices)

  hipMemsetAsync(counts, 0, N_EXPERTS * sizeof(int), stream);
  router_kernel<<<N_TOK, 64, 0, stream>>>(x, w_gate, b_gate, route_idx, route_p);
  bucket_kernel<<<N_TOK / 256, 256, 0, stream>>>(route_idx, counts, bucket);
  // layer 1: H = relu(Xg @ W1 + b1)
  expert_gemm<false><<<dim3(MLP_DIM / 128, N_TOK / 128, N_EXPERTS), 256, 0,
                       stream>>>(x, W1, b1, H, nullptr, bucket, counts,
                                 D_MODEL, MLP_DIM);
  // layer 2 pass A: raw k-slice partials (s=0 -> out, s>0 -> ws)
  expert_gemm<true><<<dim3(D_MODEL / 128, N_TOK / 128, N_EXPERTS * KSPLIT), 256,
                      0, stream>>>(H, W2, nullptr, out, partials, bucket,
                                   counts, MLP_DIM, D_MODEL);
  // layer 2 pass B: sum partials + bias + route_p scale
  moe_reduce_kernel<<<N_TOK, 256, 0, stream>>>(out, partials, b2, route_idx,
                                               route_p);
}

// Round 7
// 1268.488 us; speedup vs baseline: 1.0612x; 1.0612x over previous
//
#include <hip/hip_runtime.h>
#include <hip/hip_bf16.h>

// MoE FFN, top-1 switch routing. fp32 end-to-end (no fp32 MFMA on CDNA4).
// Sparse dispatch: each token only runs through its argmax expert (exact
// same math as the dense reference's gather of y[route_idx, arange(n)]).
//
// R5 fix (held, unbenched): grid permuted so ROW-BLOCK is the slowest
// dispatch dimension. With ~4 alive row-blocks per expert out of 32, the
// old (col,row,e) order made alive blocks alias onto a fixed CU subset
// (runs of 128 every 1024 ids, 1024%256==0) -> VALUBusy 37.7%, Occupancy
// 8.6%. Alive-first contiguous order spreads work over all 256 CUs.
//
// GEMM2 (N=1024) is split-K=4 for block parallelism; s=0 partial -> d_out,
// s=1..3 -> ws; reduce kernel applies sum + bias + route_p.
//
// Workspace: 16K +16K +256B +128K + H 64MiB + partials 48MiB = ~112.2 MiB.

#define D_MODEL 1024
#define MLP_DIM 4096
#define N_EXPERTS 8
#define N_TOK 4096
#define KSPLIT 4

// ---------------- router: logits -> softmax max prob + argmax ----------------
__global__ __launch_bounds__(64) void router_kernel(
    const float* __restrict__ x, const float* __restrict__ w_gate,
    const float* __restrict__ b_gate, int* __restrict__ route_idx,
    float* __restrict__ route_p) {
  int t = blockIdx.x;
  int lane = threadIdx.x;
  const float* xr = x + (size_t)t * D_MODEL;
  float acc[N_EXPERTS];
#pragma unroll
  for (int e = 0; e < N_EXPERTS; ++e) acc[e] = 0.f;
#pragma unroll
  for (int i = 0; i < D_MODEL / 64; ++i) {
    int idx = i * 64 + lane;
    float xv = xr[idx];
    const float* wg = w_gate + (size_t)idx * N_EXPERTS;
#pragma unroll
    for (int e = 0; e < N_EXPERTS; ++e) acc[e] += xv * wg[e];
  }
#pragma unroll
  for (int off = 32; off >= 1; off >>= 1) {
#pragma unroll
    for (int e = 0; e < N_EXPERTS; ++e) acc[e] += __shfl_xor(acc[e], off, 64);
  }
  if (lane == 0) {
    float l[N_EXPERTS];
#pragma unroll
    for (int e = 0; e < N_EXPERTS; ++e) l[e] = acc[e] + b_gate[e];
    // strict > : first-max tiebreak, matches jnp.argmax (softmax is monotonic)
    float m = l[0];
    int bi = 0;
#pragma unroll
    for (int e = 1; e < N_EXPERTS; ++e) {
      if (l[e] > m) { m = l[e]; bi = e; }
    }
    float s = 0.f;
#pragma unroll
    for (int e = 0; e < N_EXPERTS; ++e) s += expf(l[e] - m);
    route_idx[t] = bi;
    route_p[t] = 1.0f / s;  // max softmax prob = exp(0)/sum
  }
}

// ---------------- bucketize tokens per expert ----------------
__global__ void bucket_kernel(const int* __restrict__ route_idx,
                              int* __restrict__ counts,
                              int* __restrict__ bucket) {
  int t = blockIdx.x * blockDim.x + threadIdx.x;
  if (t < N_TOK) {
    int e = route_idx[t];
    int pos = atomicAdd(&counts[e], 1);
    bucket[e * N_TOK + pos] = t;
  }
}

// ---------------- gathered expert GEMM ----------------
// 128x128 tile, BK=16, 256 threads, 8x8 micro-tile as 2x2 blocks of 4x4
// (rows/cols {q*4, q*4+64}): LDS reads are broadcast + <=2-way bank alias
// (free on CDNA4, m136). Register prefetch of the next k-tile issued before
// the FMA block hides global latency under 2048 VALU-cycles of compute.
// Grid: x = col-block, y = expert (or expert*KSPLIT+s), z = ROW-BLOCK
// (slowest -> alive blocks are a contiguous dispatch prefix).
// SPLIT=false (layer 1): C = relu(A@W1 + b1) -> H
// SPLIT=true  (layer 2): raw partial A@W2 k-slice; s==0 -> d_out else ws
template <bool SPLIT>
__global__ __launch_bounds__(256) void expert_gemm(
    const float* __restrict__ A, const float* __restrict__ B,
    const float* __restrict__ bias, float* __restrict__ C0,
    float* __restrict__ partials, const int* __restrict__ bucket,
    const int* __restrict__ counts, int Kstride, int Ncols) {
  constexpr int BM = 128, BN = 128, BK = 16;
  constexpr int LDA = BM + 4, LDB = BN + 4;  // break pow2 strides
  int e, kbeg, kend;
  float* Cp;
  if (SPLIT) {
    e = blockIdx.y >> 2;
    int s = blockIdx.y & 3;
    kbeg = s * (MLP_DIM / KSPLIT);
    kend = kbeg + (MLP_DIM / KSPLIT);
    Cp = (s == 0) ? C0 : partials + (size_t)(s - 1) * N_TOK * D_MODEL;
  } else {
    e = blockIdx.y;
    kbeg = 0;
    kend = Kstride;
    Cp = C0;
  }
  int cnt = counts[e];
  int row0 = blockIdx.z * BM;   // row-block = slowest grid dim
  if (row0 >= cnt) return;
  int col0 = blockIdx.x * BN;

  __shared__ float As[BK][LDA];  // k-major (transposed store)
  __shared__ float Bs[BK][LDB];
  __shared__ int tokS[BM];

  int tid = threadIdx.x;
  if (tid < BM) {
    int r = row0 + tid;
    tokS[tid] = (r < cnt) ? bucket[e * N_TOK + r] : -1;
  }
  __syncthreads();

  // A-load map: rows {ar, ar+64}, k-chunk ak (4 floats)
  const int ar = tid >> 2;
  const int ak = (tid & 3) * 4;
  // B-load map: k-row bk, col-chunk bj (8 floats = 2 float4)
  const int bk = tid >> 4;
  const int bj = (tid & 15) * 8;

  const int tx = tid & 15;  // cols tx*4 and tx*4+64
  const int ty = tid >> 4;  // rows ty*4 and ty*4+64

  float acc[2][2][4][4];
#pragma unroll
  for (int hm = 0; hm < 2; ++hm)
#pragma unroll
    for (int hn = 0; hn < 2; ++hn)
#pragma unroll
      for (int i = 0; i < 4; ++i)
#pragma unroll
        for (int j = 0; j < 4; ++j) acc[hm][hn][i][j] = 0.f;

  const int tok0 = tokS[ar], tok1 = tokS[ar + 64];
  const float* __restrict__ Ap0 =
      (tok0 >= 0) ? A + (size_t)tok0 * Kstride + ak : nullptr;
  const float* __restrict__ Ap1 =
      (tok1 >= 0) ? A + (size_t)tok1 * Kstride + ak : nullptr;
  const float* __restrict__ Bp =
      B + (size_t)e * Kstride * Ncols + (size_t)bk * Ncols + col0 + bj;

  float4 a0, a1, b0, b1;
  a0 = make_float4(0.f, 0.f, 0.f, 0.f);
  a1 = a0;
  if (Ap0) a0 = *(const float4*)(Ap0 + kbeg);
  if (Ap1) a1 = *(const float4*)(Ap1 + kbeg);
  {
    const float* bp = Bp + (size_t)kbeg * Ncols;
    b0 = *(const float4*)bp;
    b1 = *(const float4*)(bp + 4);
  }

  for (int k0 = kbeg; k0 < kend; k0 += BK) {
    __syncthreads();  // previous compute done before overwrite
    As[ak + 0][ar] = a0.x; As[ak + 1][ar] = a0.y;
    As[ak + 2][ar] = a0.z; As[ak + 3][ar] = a0.w;
    As[ak + 0][ar + 64] = a1.x; As[ak + 1][ar + 64] = a1.y;
    As[ak + 2][ar + 64] = a1.z; As[ak + 3][ar + 64] = a1.w;
    *(float4*)&Bs[bk][bj] = b0;
    *(float4*)&Bs[bk][bj + 4] = b1;
    __syncthreads();

    if (k0 + BK < kend) {  // prefetch next tile into regs (overlaps compute)
      int kn = k0 + BK;
      a0 = make_float4(0.f, 0.f, 0.f, 0.f);
      a1 = a0;
      if (Ap0) a0 = *(const float4*)(Ap0 + kn);
      if (Ap1) a1 = *(const float4*)(Ap1 + kn);
      const float* bp = Bp + (size_t)kn * Ncols;
      b0 = *(const float4*)bp;
      b1 = *(const float4*)(bp + 4);
    }

#pragma unroll
    for (int kk = 0; kk < BK; ++kk) {
      float av[2][4], bv[2][4];
      *(float4*)&av[0][0] = *(const float4*)&As[kk][ty * 4];
      *(float4*)&av[1][0] = *(const float4*)&As[kk][ty * 4 + 64];
      *(float4*)&bv[0][0] = *(const float4*)&Bs[kk][tx * 4];
      *(float4*)&bv[1][0] = *(const float4*)&Bs[kk][tx * 4 + 64];
#pragma unroll
      for (int hm = 0; hm < 2; ++hm)
#pragma unroll
        for (int hn = 0; hn < 2; ++hn)
#pragma unroll
          for (int i = 0; i < 4; ++i)
#pragma unroll
            for (int j = 0; j < 4; ++j)
              acc[hm][hn][i][j] += av[hm][i] * bv[hn][j];
    }
  }

  if (SPLIT) {
    // raw k-slice partial, no bias/epilogue
#pragma unroll
    for (int hm = 0; hm < 2; ++hm) {
#pragma unroll
      for (int i = 0; i < 4; ++i) {
        int r = hm * 64 + ty * 4 + i;
        if (row0 + r < cnt) {
          int tok = tokS[r];
#pragma unroll
          for (int hn = 0; hn < 2; ++hn) {
            float4 o;
            o.x = acc[hm][hn][i][0]; o.y = acc[hm][hn][i][1];
            o.z = acc[hm][hn][i][2]; o.w = acc[hm][hn][i][3];
            *(float4*)(Cp + (size_t)tok * Ncols + col0 + hn * 64 + tx * 4) = o;
          }
        }
      }
    }
  } else {
    float4 bvv[2];
    bvv[0] = *(const float4*)(bias + (size_t)e * Ncols + col0 + tx * 4);
    bvv[1] = *(const float4*)(bias + (size_t)e * Ncols + col0 + tx * 4 + 64);
#pragma unroll
    for (int hm = 0; hm < 2; ++hm) {
#pragma unroll
      for (int i = 0; i < 4; ++i) {
        int r = hm * 64 + ty * 4 + i;
        if (row0 + r < cnt) {
          int tok = tokS[r];
#pragma unroll
          for (int hn = 0; hn < 2; ++hn) {
            const float* bb = (const float*)&bvv[hn];
            float4 o;
            o.x = fmaxf(acc[hm][hn][i][0] + bb[0], 0.f);
            o.y = fmaxf(acc[hm][hn][i][1] + bb[1], 0.f);
            o.z = fmaxf(acc[hm][hn][i][2] + bb[2], 0.f);
            o.w = fmaxf(acc[hm][hn][i][3] + bb[3], 0.f);
            *(float4*)(Cp + (size_t)tok * Ncols + col0 + hn * 64 + tx * 4) = o;
          }
        }
      }
    }
  }
}

// ---------------- split-K reduce + bias + route_p epilogue ----------------
// one block per token, 256 threads = 256 float4 covering D_MODEL=1024 cols.
__global__ __launch_bounds__(256) void moe_reduce_kernel(
    float* __restrict__ out, const float* __restrict__ partials,
    const float* __restrict__ b2, const int* __restrict__ route_idx,
    const float* __restrict__ route_p) {
  int tok = blockIdx.x;
  int c = threadIdx.x * 4;
  int e = route_idx[tok];
  float p = route_p[tok];
  size_t off = (size_t)tok * D_MODEL + c;
  float4 s = *(const float4*)(out + off);
  const size_t stride = (size_t)N_TOK * D_MODEL;
#pragma unroll
  for (int sp = 0; sp < KSPLIT - 1; ++sp) {
    float4 v = *(const float4*)(partials + sp * stride + off);
    s.x += v.x; s.y += v.y; s.z += v.z; s.w += v.w;
  }
  float4 bv = *(const float4*)(b2 + (size_t)e * D_MODEL + c);
  s.x = (s.x + bv.x) * p;
  s.y = (s.y + bv.y) * p;
  s.z = (s.z + bv.z) * p;
  s.w = (s.w + bv.w) * p;
  *(float4*)(out + off) = s;
}

extern "C" void kernel_launch(void* const* d_in, const int* in_sizes, int n_in,
                              void* d_out, int out_size, void* d_ws,
                              size_t ws_size, hipStream_t stream) {
  const float* x = (const float*)d_in[0];
  const float* w_gate = (const float*)d_in[1];
  const float* b_gate = (const float*)d_in[2];
  const float* W1 = (const float*)d_in[3];
  const float* b1 = (const float*)d_in[4];
  const float* W2 = (const float*)d_in[5];
  const float* b2 = (const float*)d_in[6];
  float* out = (float*)d_out;

  // workspace layout (~112.2 MiB)
  char* ws = (char*)d_ws;
  int* route_idx = (int*)ws;                        // 16 KiB
  float* route_p = (float*)(ws + 16384);            // 16 KiB
  int* counts = (int*)(ws + 32768);                 // 32 B (pad to 256)
  int* bucket = (int*)(ws + 33024);                 // 128 KiB
  float* H = (float*)(ws + 164096);                 // 64 MiB
  float* partials = (float*)(ws + 164096 + (size_t)67108864);  // 48 MiB (3 slices)

  hipMemsetAsync(counts, 0, N_EXPERTS * sizeof(int), stream);
  router_kernel<<<N_TOK, 64, 0, stream>>>(x, w_gate, b_gate, route_idx, route_p);
  bucket_kernel<<<N_TOK / 256, 256, 0, stream>>>(route_idx, counts, bucket);
  // layer 1: H = relu(Xg @ W1 + b1)
  // grid: (col=32, expert=8, rowblk=32) — rowblk slowest => alive prefix
  expert_gemm<false><<<dim3(MLP_DIM / 128, N_EXPERTS, N_TOK / 128), 256, 0,
                       stream>>>(x, W1, b1, H, nullptr, bucket, counts,
                                 D_MODEL, MLP_DIM);
  // layer 2 pass A: raw k-slice partials (s=0 -> out, s>0 -> ws)
  // grid: (col=8, expert*KSPLIT=32, rowblk=32) — rowblk slowest
  expert_gemm<true><<<dim3(D_MODEL / 128, N_EXPERTS * KSPLIT, N_TOK / 128), 256,
                      0, stream>>>(H, W2, nullptr, out, partials, bucket,
                                   counts, MLP_DIM, D_MODEL);
  // layer 2 pass B: sum partials + bias + route_p scale
  moe_reduce_kernel<<<N_TOK, 256, 0, stream>>>(out, partials, b2, route_idx,
                                               route_p);
}